// Round 7
// baseline (21.020 us; speedup 1.0000x reference)
//
#include <hip/hip_runtime.h>
#include <math.h>

#define NKEYS 8192
#define NBINS 128
#define NFREQ 64
#define NKER  3
#define HEADD 128

// Fourier expansion: e^{k(cos d - 1)} = e^-k [I0(k) + 2 sum_m Im(k) cos(m d)]
// kappa <= 1 -> M=4 truncation ~2e-4 relative (verified absmax 0.031 vs 0.152).
#define MHARM 4
#define NCH   9                    // {1, cos m, sin m}, m=1..4
#define KDIM  (NCH * NFREQ)        // 576
#define KSTEPS (KDIM / 32)         // 18 MFMA K-steps

// Fragment-order k-mapping (16x16x32 f16 MFMA, verified in rounds 3-6):
//   k_global = kt*32 + q*8 + j  (q = lane>>4, j = 0..7)
//   (ch, f) <-> kt = ch*2 + (f>>5), q = (f>>3)&3, j = f&7   (bijective)

typedef _Float16 f16x8 __attribute__((ext_vector_type(8)));
typedef float    f32x4 __attribute__((ext_vector_type(4)));

// ---------------------------------------------------------------------------
// Kernel A: coefficient table in B-fragment order (each term computed ONCE):
//   Bswz[ ((g*KSTEPS + kt)*64 + q*16 + lc)*8 + j ] = C[col=g*16+lc][kt*32+q*8+j]
// One thread per (bin, freq); 128 blocks of 64 threads. 144 KiB, L2-resident.
// ---------------------------------------------------------------------------
__global__ void build_coeffs(const float* __restrict__ refang,
                             const float* __restrict__ mu,
                             const float* __restrict__ kappa,
                             const float* __restrict__ weight,
                             _Float16* __restrict__ Bswz) {
    int gid = blockIdx.x * blockDim.x + threadIdx.x;
    if (gid >= NBINS * NFREQ) return;
    int b = gid >> 6, f = gid & 63;
    float rf = refang[f];

    float acc[NCH];
    #pragma unroll
    for (int c = 0; c < NCH; ++c) acc[c] = 0.f;

    #pragma unroll
    for (int k = 0; k < NKER; ++k) {
        int idx = (b * NFREQ + f) * NKER + k;
        float me  = mu[idx] + rf;
        float kap = kappa[idx];
        float w   = weight[idx];
        float h = 0.5f * kap, h2 = h * h;
        float wek = w * __expf(-kap);
        float c1, s1;
        __sincosf(me, &s1, &c1);

        // modified Bessel I_0..I_4 via series (x<=0.5: ~1e-10)
        float Im[MHARM + 1];
        float tm = 1.f;                       // h^m / m!
        #pragma unroll
        for (int m = 0; m <= MHARM; ++m) {
            float t = tm, s = tm;
            #pragma unroll
            for (int j = 1; j <= 5; ++j) { t *= h2 / (float)(j * (m + j)); s += t; }
            Im[m] = s;
            tm *= h / (float)(m + 1);
        }

        acc[0] += wek * Im[0];
        float cp = 1.f, sp = 0.f, cc = c1, sc = s1;  // cos/sin(m*me) recurrence
        #pragma unroll
        for (int m = 1; m <= MHARM; ++m) {
            float g = 2.f * wek * Im[m];
            acc[2 * m - 1] += g * cc;
            acc[2 * m]     += g * sc;
            float cn = fmaf(2.f * c1, cc, -cp);
            float sn = fmaf(2.f * c1, sc, -sp);
            cp = cc; sp = sc; cc = cn; sc = sn;
        }
    }

    const int g = b >> 4, lc = b & 15;
    const int q = (f >> 3) & 3, j = f & 7;
    #pragma unroll
    for (int c = 0; c < NCH; ++c) {
        int kt = c * 2 + (f >> 5);
        Bswz[((size_t)(g * KSTEPS + kt) * 64 + q * 16 + lc) * 8 + j] = (_Float16)acc[c];
    }
}

// ---------------------------------------------------------------------------
// Kernel B: 1-wave blocks, 16 rows x 16 cols each. A-features in REGISTERS
// (lane (q,lc): row lc, freqs {h*32+q*8+j}), B from table (1 KB/wave/kt,
// L2-hot), 18 MFMAs, store. No LDS, no barriers. Grid 4096 = 16 blocks/CU
// queued; __launch_bounds__(64,3) keeps >=3 waves/SIMD resident.
// Block order: rowblk = bid&511 -> rowblk r pinned to XCD r%8 across all
// col-groups g = bid>>9 -> K re-reads stay in the same XCD's L2.
// ---------------------------------------------------------------------------
__global__ __launch_bounds__(64, 3) void gemm_inreg(
    const float* __restrict__ K,
    const _Float16* __restrict__ Bswz,
    const float* __restrict__ bias,
    float* __restrict__ out)
{
    const int lane = threadIdx.x;
    const int q = lane >> 4, lc = lane & 15;
    const int bid = blockIdx.x;
    const int g = bid >> 9;                  // col group 0..7
    const int rowblk = bid & 511;
    const int row = rowblk * 16 + lc;

    // --- A-features for row `row`, 16 freqs (two halves of 8), in regs ---
    f16x8 afrag[KSTEPS];
    const float* kp = K + (size_t)row * HEADD + q * 16;
    #pragma unroll
    for (int h = 0; h < 2; ++h) {
        const float4* ldp = (const float4*)(kp + h * 64);
        const float4 p0 = ldp[0], p1 = ldp[1], p2 = ldp[2], p3 = ldp[3];
        const float xs[8] = {p0.x, p0.z, p1.x, p1.z, p2.x, p2.z, p3.x, p3.z};
        const float ys[8] = {p0.y, p0.w, p1.y, p1.w, p2.y, p2.w, p3.y, p3.w};
        float mag[8], c1[8], cc[8], sc[8], cp[8], sp[8];
        #pragma unroll
        for (int i = 0; i < 8; ++i) {
            float m2 = xs[i] * xs[i] + ys[i] * ys[i];
            float ri = (m2 > 0.f) ? rsqrtf(m2) : 0.f;
            mag[i] = m2 * ri;
            c1[i] = xs[i] * ri;
            float s1 = ys[i] * ri;
            cp[i] = 1.f; sp[i] = 0.f; cc[i] = c1[i]; sc[i] = s1;
            afrag[h][i] = (_Float16)mag[i];                       // ch 0
        }
        #pragma unroll
        for (int m = 1; m <= MHARM; ++m) {
            #pragma unroll
            for (int i = 0; i < 8; ++i) {
                afrag[(2 * m - 1) * 2 + h][i] = (_Float16)(mag[i] * cc[i]);
                afrag[(2 * m) * 2 + h][i]     = (_Float16)(mag[i] * sc[i]);
                float cn = fmaf(2.f * c1[i], cc[i], -cp[i]);
                float sn = fmaf(2.f * c1[i], sc[i], -sp[i]);
                cp[i] = cc[i]; sp[i] = sc[i]; cc[i] = cn; sc[i] = sn;
            }
        }
    }

    // --- GEMM: 18 K-steps, B-frag = contiguous 1 KB per wave per step ---
    const f16x8* bp = (const f16x8*)Bswz + (size_t)g * KSTEPS * 64 + lane;
    f32x4 acc = {0.f, 0.f, 0.f, 0.f};
    #pragma unroll
    for (int kt = 0; kt < KSTEPS; ++kt) {
        f16x8 b = bp[kt * 64];
        acc = __builtin_amdgcn_mfma_f32_16x16x32_f16(afrag[kt], b, acc, 0, 0, 0);
    }

    // C/D layout: col = lane&15, row = (lane>>4)*4 + reg
    const int col = g * 16 + lc;
    const float bb = bias[col];
    #pragma unroll
    for (int jj = 0; jj < 4; ++jj)
        out[(size_t)(rowblk * 16 + q * 4 + jj) * NBINS + col] = acc[jj] + bb;
}

// ---------------------------------------------------------------------------
// Fallback (ws too small for Bswz): direct form, inline trig.
// ---------------------------------------------------------------------------
#define KPB 16
#define FTHREADS 512
#define KPT 4
#define KV_STRIDE (KPB + 1)
#define LOG2E 1.44269504088896340736f

__global__ __launch_bounds__(FTHREADS) void vonmises_fallback(
    const float* __restrict__ K,
    const float* __restrict__ refang,
    const float* __restrict__ mu,
    const float* __restrict__ kappa,
    const float* __restrict__ weight,
    const float* __restrict__ bias,
    float* __restrict__ out)
{
    __shared__ float4 kvlds[NFREQ * KV_STRIDE];
    const int tid  = threadIdx.x;
    const int key0 = blockIdx.x * KPB;

    for (int p = tid; p < KPB * NFREQ; p += FTHREADS) {
        int key = p >> 6, f = p & (NFREQ - 1);
        const float2 xy = *(const float2*)(K + (size_t)(key0 + key) * HEADD + 2 * f);
        float m2 = xy.x * xy.x + xy.y * xy.y;
        float rm = (m2 > 0.f) ? rsqrtf(m2) : 0.f;
        kvlds[f * KV_STRIDE + key] = make_float4(xy.x * rm, xy.y * rm, m2 * rm, 0.f);
    }
    __syncthreads();

    const int bin = tid & (NBINS - 1);
    const int kbase = (tid >> 7) * KPT;
    float acc[KPT] = {0.f, 0.f, 0.f, 0.f};

    for (int f = 0; f < NFREQ; ++f) {
        float4 kv[KPT];
        #pragma unroll
        for (int j = 0; j < KPT; ++j) kv[j] = kvlds[f * KV_STRIDE + kbase + j];
        float wk[KPT] = {0.f, 0.f, 0.f, 0.f};
        #pragma unroll
        for (int k = 0; k < NKER; ++k) {
            int idx = (bin * NFREQ + f) * NKER + k;
            float me = mu[idx] + refang[f];
            float ka = kappa[idx] * LOG2E;
            float s, c;
            __sincosf(me, &s, &c);
            #pragma unroll
            for (int j = 0; j < KPT; ++j) {
                float t = fmaf(kv[j].x, ka * c, fmaf(kv[j].y, ka * s, -ka));
                wk[j] = fmaf(exp2f(t), weight[idx], wk[j]);
            }
        }
        #pragma unroll
        for (int j = 0; j < KPT; ++j) acc[j] = fmaf(wk[j], kv[j].z, acc[j]);
    }
    const float bb = bias[bin];
    #pragma unroll
    for (int j = 0; j < KPT; ++j)
        out[(size_t)(key0 + kbase + j) * NBINS + bin] = acc[j] + bb;
}

// ---------------------------------------------------------------------------
extern "C" void kernel_launch(void* const* d_in, const int* in_sizes, int n_in,
                              void* d_out, int out_size, void* d_ws, size_t ws_size,
                              hipStream_t stream) {
    const float* K      = (const float*)d_in[0];
    const float* refang = (const float*)d_in[1];
    const float* mu     = (const float*)d_in[2];
    const float* kappa  = (const float*)d_in[3];
    const float* weight = (const float*)d_in[4];
    const float* bias   = (const float*)d_in[5];
    float* out = (float*)d_out;

    const size_t need = (size_t)NBINS * KDIM * sizeof(_Float16);   // 144 KiB

    if (ws_size >= need) {
        _Float16* Bswz = (_Float16*)d_ws;
        build_coeffs<<<NBINS * NFREQ / 64, 64, 0, stream>>>(
            refang, mu, kappa, weight, Bswz);
        gemm_inreg<<<512 * 8, 64, 0, stream>>>(K, Bswz, bias, out);
    } else {
        vonmises_fallback<<<NKEYS / KPB, FTHREADS, 0, stream>>>(
            K, refang, mu, kappa, weight, bias, out);
    }
}

// Round 8
// 16.996 us; speedup vs baseline: 1.2367x; 1.2367x over previous
//
#include <hip/hip_runtime.h>
#include <math.h>

#define NKEYS 8192
#define NBINS 128
#define NFREQ 64
#define NKER  3
#define HEADD 128

// Fourier expansion: e^{k(cos d - 1)} = e^-k [I0(k) + 2 sum_m Im(k) cos(m d)]
// kappa <= 1, M=4 truncation ~2e-4 relative (verified: absmax 0.031 vs 0.152).
#define MHARM 4
#define NCH   9                    // {1, cos m, sin m}, m=1..4
#define KDIM  (NCH * NFREQ)        // 576
#define KSTEPS (KDIM / 32)         // 18 MFMA K-steps

// Fragment-order k-mapping (16x16x32 f16 MFMA, verified rounds 3-7):
//   k_global = kt*32 + q*8 + j  (q = lane>>4, j = 0..7)
//   (ch, f) <-> kt = ch*2 + (f>>5), q = (f>>3)&3, j = f&7   (bijective)
// A-operand lane role: row = lane&15, k-quarter = lane>>4  (same index form).

typedef _Float16 f16x8 __attribute__((ext_vector_type(8)));
typedef float    f32x4 __attribute__((ext_vector_type(4)));

#define BOFF 0                         // Bswz at d_ws + 0 (144 KiB)
#define AOFF (1 << 20)                 // A-table at d_ws + 1 MiB (9.44 MiB)
#define ATAB_F16X8_PER_RC (KSTEPS * 64)   // 1152 f16x8 per 16-row chunk

// ---------------------------------------------------------------------------
// Prep kernel (single dispatch, mixed roles per block):
//   blocks [0,32):    B-coeff table, fragment order, each term computed once.
//   blocks [32,288):  A-feature table, fragment order, fp16.
// ---------------------------------------------------------------------------
__global__ __launch_bounds__(256) void prep_tables(
    const float* __restrict__ K,
    const float* __restrict__ refang,
    const float* __restrict__ mu,
    const float* __restrict__ kappa,
    const float* __restrict__ weight,
    _Float16* __restrict__ Bswz,
    _Float16* __restrict__ Atab)
{
    const int bid = blockIdx.x, tid = threadIdx.x;

    if (bid < 32) {
        // ---------------- B-coefficient table (8192 jobs) ----------------
        const int gid = bid * 256 + tid;
        const int b = gid >> 6, f = gid & 63;
        const float rf = refang[f];

        float acc[NCH];
        #pragma unroll
        for (int c = 0; c < NCH; ++c) acc[c] = 0.f;

        #pragma unroll
        for (int k = 0; k < NKER; ++k) {
            const int idx = (b * NFREQ + f) * NKER + k;
            const float me  = mu[idx] + rf;
            const float kap = kappa[idx];
            const float w   = weight[idx];
            const float h = 0.5f * kap, h2 = h * h;
            const float wek = w * __expf(-kap);
            float s1, c1;
            __sincosf(me, &s1, &c1);

            float Im[MHARM + 1];
            float tm = 1.f;                       // h^m / m!
            #pragma unroll
            for (int m = 0; m <= MHARM; ++m) {
                float t = tm, s = tm;
                #pragma unroll
                for (int j = 1; j <= 5; ++j) { t *= h2 / (float)(j * (m + j)); s += t; }
                Im[m] = s;
                tm *= h / (float)(m + 1);
            }

            acc[0] += wek * Im[0];
            float cp = 1.f, sp = 0.f, cc = c1, sc = s1;
            #pragma unroll
            for (int m = 1; m <= MHARM; ++m) {
                const float g = 2.f * wek * Im[m];
                acc[2 * m - 1] += g * cc;
                acc[2 * m]     += g * sc;
                const float cn = fmaf(2.f * c1, cc, -cp);
                const float sn = fmaf(2.f * c1, sc, -sp);
                cp = cc; sp = sc; cc = cn; sc = sn;
            }
        }

        const int g = b >> 4, lc = b & 15;
        const int q = (f >> 3) & 3, j = f & 7;
        #pragma unroll
        for (int c = 0; c < NCH; ++c) {
            const int kt = c * 2 + (f >> 5);
            Bswz[((size_t)(g * KSTEPS + kt) * 64 + q * 16 + lc) * 8 + j] = (_Float16)acc[c];
        }
    } else {
        // ---------------- A-feature table (65536 octet jobs) ----------------
        const int job = (bid - 32) * 256 + tid;     // 0..65535
        const int n  = job >> 3;                    // key row 0..8191
        const int oc = job & 7;                     // freq octet 0..7
        const int qa = oc & 3, half = oc >> 2;
        const int rc = n >> 4, lcn = n & 15;

        const float4* ldp = (const float4*)(K + (size_t)n * HEADD + oc * 16);
        const float4 p0 = ldp[0], p1 = ldp[1], p2 = ldp[2], p3 = ldp[3];
        const float xs[8] = {p0.x, p0.z, p1.x, p1.z, p2.x, p2.z, p3.x, p3.z};
        const float ys[8] = {p0.y, p0.w, p1.y, p1.w, p2.y, p2.w, p3.y, p3.w};

        float mag[8], c1[8], cc[8], sc[8], cp[8], sp[8];
        f16x8 v;
        #pragma unroll
        for (int i = 0; i < 8; ++i) {
            const float m2 = xs[i] * xs[i] + ys[i] * ys[i];
            const float ri = (m2 > 0.f) ? rsqrtf(m2) : 0.f;
            mag[i] = m2 * ri;
            c1[i] = xs[i] * ri;
            const float s1 = ys[i] * ri;
            cp[i] = 1.f; sp[i] = 0.f; cc[i] = c1[i]; sc[i] = s1;
            v[i] = (_Float16)mag[i];
        }
        _Float16* base = Atab + (size_t)rc * (KSTEPS * 512) + half * 512
                              + (qa * 16 + lcn) * 8;
        *(f16x8*)base = v;                                   // ch 0, kt = half
        #pragma unroll
        for (int m = 1; m <= MHARM; ++m) {
            f16x8 vc, vs;
            #pragma unroll
            for (int i = 0; i < 8; ++i) {
                vc[i] = (_Float16)(mag[i] * cc[i]);
                vs[i] = (_Float16)(mag[i] * sc[i]);
                const float cn = fmaf(2.f * c1[i], cc[i], -cp[i]);
                const float sn = fmaf(2.f * c1[i], sc[i], -sp[i]);
                cp[i] = cc[i]; sp[i] = sc[i]; cc[i] = cn; sc[i] = sn;
            }
            *(f16x8*)(base + (2 * m - 1) * 1024) = vc;       // kt = (2m-1)*2+half
            *(f16x8*)(base + (2 * m) * 1024)     = vs;       // kt = (2m)*2+half
        }
    }
}

// ---------------------------------------------------------------------------
// GEMM kernel: pure load+MFMA, no LDS, no barriers, no transcendentals.
// 1024 blocks x 256 threads (4 waves). Block -> 2 rowchunks x 2 colgroups;
// wave w -> rc = rc0+(w&1), g = g0+(w>>1). Per wave: 18 x (16B A-load +
// 16B B-load + MFMA), then bias + 4 stores. ~36 independent loads in flight.
// bid&255 = rcpair -> XCD pinning: all 4 blocks reading a given rcpair land
// on the same XCD (256%8==0), so A-slices stay in one L2.
// ---------------------------------------------------------------------------
__global__ __launch_bounds__(256, 4) void gemm_tab(
    const _Float16* __restrict__ Atab,
    const _Float16* __restrict__ Bswz,
    const float* __restrict__ bias,
    float* __restrict__ out)
{
    const int tid  = threadIdx.x;
    const int lane = tid & 63, w = tid >> 6;
    const int bid  = blockIdx.x;
    const int rc   = (bid & 255) * 2 + (w & 1);      // rowchunk 0..511
    const int g    = (bid >> 8) * 2 + (w >> 1);      // colgroup 0..7

    const f16x8* ap = (const f16x8*)Atab + (size_t)rc * ATAB_F16X8_PER_RC + lane;
    const f16x8* bp = (const f16x8*)Bswz + (size_t)g  * ATAB_F16X8_PER_RC + lane;

    f32x4 acc = {0.f, 0.f, 0.f, 0.f};
    #pragma unroll
    for (int kt = 0; kt < KSTEPS; ++kt) {
        const f16x8 a = ap[kt * 64];                 // contiguous 1 KB per wave
        const f16x8 b = bp[kt * 64];                 // contiguous 1 KB per wave
        acc = __builtin_amdgcn_mfma_f32_16x16x32_f16(a, b, acc, 0, 0, 0);
    }

    // C/D layout: col = lane&15, row = (lane>>4)*4 + reg
    const int q = lane >> 4, lc = lane & 15;
    const int col = g * 16 + lc;
    const float bb = bias[col];
    #pragma unroll
    for (int jj = 0; jj < 4; ++jj)
        out[(size_t)(rc * 16 + q * 4 + jj) * NBINS + col] = acc[jj] + bb;
}

// ---------------------------------------------------------------------------
// Fallback (ws too small): direct form, inline trig. Known-correct.
// ---------------------------------------------------------------------------
#define KPB 16
#define FTHREADS 512
#define KPT 4
#define KV_STRIDE (KPB + 1)
#define LOG2E 1.44269504088896340736f

__global__ __launch_bounds__(FTHREADS) void vonmises_fallback(
    const float* __restrict__ K,
    const float* __restrict__ refang,
    const float* __restrict__ mu,
    const float* __restrict__ kappa,
    const float* __restrict__ weight,
    const float* __restrict__ bias,
    float* __restrict__ out)
{
    __shared__ float4 kvlds[NFREQ * KV_STRIDE];
    const int tid  = threadIdx.x;
    const int key0 = blockIdx.x * KPB;

    for (int p = tid; p < KPB * NFREQ; p += FTHREADS) {
        int key = p >> 6, f = p & (NFREQ - 1);
        const float2 xy = *(const float2*)(K + (size_t)(key0 + key) * HEADD + 2 * f);
        float m2 = xy.x * xy.x + xy.y * xy.y;
        float rm = (m2 > 0.f) ? rsqrtf(m2) : 0.f;
        kvlds[f * KV_STRIDE + key] = make_float4(xy.x * rm, xy.y * rm, m2 * rm, 0.f);
    }
    __syncthreads();

    const int bin = tid & (NBINS - 1);
    const int kbase = (tid >> 7) * KPT;
    float acc[KPT] = {0.f, 0.f, 0.f, 0.f};

    for (int f = 0; f < NFREQ; ++f) {
        float4 kv[KPT];
        #pragma unroll
        for (int j = 0; j < KPT; ++j) kv[j] = kvlds[f * KV_STRIDE + kbase + j];
        float wk[KPT] = {0.f, 0.f, 0.f, 0.f};
        #pragma unroll
        for (int k = 0; k < NKER; ++k) {
            int idx = (bin * NFREQ + f) * NKER + k;
            float me = mu[idx] + refang[f];
            float ka = kappa[idx] * LOG2E;
            float s, c;
            __sincosf(me, &s, &c);
            #pragma unroll
            for (int j = 0; j < KPT; ++j) {
                float t = fmaf(kv[j].x, ka * c, fmaf(kv[j].y, ka * s, -ka));
                wk[j] = fmaf(exp2f(t), weight[idx], wk[j]);
            }
        }
        #pragma unroll
        for (int j = 0; j < KPT; ++j) acc[j] = fmaf(wk[j], kv[j].z, acc[j]);
    }
    const float bb = bias[bin];
    #pragma unroll
    for (int j = 0; j < KPT; ++j)
        out[(size_t)(key0 + kbase + j) * NBINS + bin] = acc[j] + bb;
}

// ---------------------------------------------------------------------------
extern "C" void kernel_launch(void* const* d_in, const int* in_sizes, int n_in,
                              void* d_out, int out_size, void* d_ws, size_t ws_size,
                              hipStream_t stream) {
    const float* K      = (const float*)d_in[0];
    const float* refang = (const float*)d_in[1];
    const float* mu     = (const float*)d_in[2];
    const float* kappa  = (const float*)d_in[3];
    const float* weight = (const float*)d_in[4];
    const float* bias   = (const float*)d_in[5];
    float* out = (float*)d_out;

    const size_t need = AOFF + (size_t)512 * KSTEPS * 512 * sizeof(_Float16); // ~10.4 MiB

    if (ws_size >= need) {
        _Float16* Bswz = (_Float16*)((char*)d_ws + BOFF);
        _Float16* Atab = (_Float16*)((char*)d_ws + AOFF);
        prep_tables<<<288, 256, 0, stream>>>(K, refang, mu, kappa, weight, Bswz, Atab);
        gemm_tab<<<1024, 256, 0, stream>>>(Atab, Bswz, bias, out);
    } else {
        vonmises_fallback<<<NKEYS / KPB, FTHREADS, 0, stream>>>(
            K, refang, mu, kappa, weight, bias, out);
    }
}